// Round 4
// baseline (625.333 us; speedup 1.0000x reference)
//
#include <hip/hip_runtime.h>

#define NN 50000
#define NE 800000
#define F  128
#define NB 2

typedef __attribute__((ext_vector_type(8))) short     bf16x8;
typedef __attribute__((ext_vector_type(4))) float     f32x4;
typedef __attribute__((ext_vector_type(8))) unsigned short u16x8;
typedef __attribute__((ext_vector_type(4))) unsigned short u16x4;

__device__ inline unsigned short f2bf_rn(float f) {
    unsigned u = __float_as_uint(f);
    u += 0x7FFFu + ((u >> 16) & 1u);
    return (unsigned short)(u >> 16);
}
__device__ inline float bf2f(unsigned short h) {
    return __uint_as_float(((unsigned)h) << 16);
}

// ---------------- CSR build ----------------

__global__ void count_kernel(const int* __restrict__ dst, int* __restrict__ cnt) {
    int e = blockIdx.x * blockDim.x + threadIdx.x;
    if (e < NE) atomicAdd(&cnt[dst[e]], 1);
}

__global__ __launch_bounds__(1024) void scan1_kernel(const int* __restrict__ cnt,
                                                     int* __restrict__ local_ex,
                                                     int* __restrict__ blocksums) {
    __shared__ int sd[1024];
    int i = blockIdx.x * 1024 + threadIdx.x;
    int v = (i < NN) ? cnt[i] : 0;
    sd[threadIdx.x] = v;
    __syncthreads();
    for (int off = 1; off < 1024; off <<= 1) {
        int t = 0;
        if ((int)threadIdx.x >= off) t = sd[threadIdx.x - off];
        __syncthreads();
        sd[threadIdx.x] += t;
        __syncthreads();
    }
    if (i < NN) local_ex[i] = sd[threadIdx.x] - v;  // exclusive within block
    if (threadIdx.x == 1023) blocksums[blockIdx.x] = sd[1023];
}

__global__ void scan2_kernel(int* __restrict__ bs, int nb) {
    int lane = threadIdx.x;
    int v = (lane < nb) ? bs[lane] : 0;
    for (int off = 1; off < 64; off <<= 1) {
        int t = __shfl_up(v, off);
        if (lane >= off) v += t;
    }
    int ex = __shfl_up(v, 1);
    if (lane == 0) ex = 0;
    if (lane < nb) bs[lane] = ex;
}

__global__ void scan3_kernel(const int* __restrict__ local_ex, const int* __restrict__ bs,
                             const int* __restrict__ cnt,
                             int* __restrict__ rowptr, float* __restrict__ dinv) {
    int i = blockIdx.x * blockDim.x + threadIdx.x;
    if (i < NN) {
        rowptr[i] = local_ex[i] + bs[i >> 10];
        int d = cnt[i];
        dinv[i] = (d > 0) ? 1.0f / (float)d : 0.0f;
    }
    if (i == 0) rowptr[NN] = NE;
}

__global__ void fill_kernel(const int* __restrict__ src, const int* __restrict__ dst,
                            const int* __restrict__ rowptr, int* __restrict__ cursor,
                            int* __restrict__ eidx) {
    int e = blockIdx.x * blockDim.x + threadIdx.x;
    if (e < NE) {
        int d = dst[e];
        int p = rowptr[d] + atomicAdd(&cursor[d], 1);
        __builtin_nontemporal_store(src[e], &eidx[p]);  // scattered 4B: skip L2 write-allocate
    }
}

// ---------------- weight split (all 3 layers) ----------------

__global__ void wsplit_kernel(const float* __restrict__ Ws0, const float* __restrict__ Wn0,
                              const float* __restrict__ Ws1, const float* __restrict__ Wn1,
                              const float* __restrict__ Ws2, const float* __restrict__ Wn2,
                              unsigned short* __restrict__ hi, unsigned short* __restrict__ lo) {
    int idx = blockIdx.x * blockDim.x + threadIdx.x;  // 3*128*256
    int l = idx >> 15;
    int r = idx & 32767;
    int j = r >> 8, k = r & 255;
    const float* Ws = (l == 0) ? Ws0 : (l == 1) ? Ws1 : Ws2;
    const float* Wn = (l == 0) ? Wn0 : (l == 1) ? Wn1 : Wn2;
    float v = (k < 128) ? Ws[j * 128 + k] : Wn[j * 128 + (k - 128)];
    unsigned short h = f2bf_rn(v);
    hi[idx] = h;
    lo[idx] = f2bf_rn(v - bf2f(h));
}

// ---------------- x split: fp32 -> hi/lo bf16 (both batches, one launch) ----------------

__global__ void xsplit_kernel(const float* __restrict__ x,
                              unsigned short* __restrict__ hi, unsigned short* __restrict__ lo) {
    size_t idx = (size_t)blockIdx.x * blockDim.x + threadIdx.x;  // NB*NN*F/4 threads
    float4 v = *reinterpret_cast<const float4*>(&x[idx * 4]);
    u16x4 h4, l4;
    float vv[4] = {v.x, v.y, v.z, v.w};
#pragma unroll
    for (int i = 0; i < 4; ++i) {
        unsigned short h = f2bf_rn(vv[i]);
        h4[i] = h;
        l4[i] = f2bf_rn(vv[i] - bf2f(h));
    }
    *reinterpret_cast<u16x4*>(&hi[idx * 4]) = h4;
    *reinterpret_cast<u16x4*>(&lo[idx * 4]) = l4;
}

// ---------------- fused layer: aggregate(LDS) + MFMA GEMM + bias + relu ----------------
// Block: 128 dst nodes x 128 out cols, 512 threads = 8 waves (4 wm x 2 wn).
// Phase 1: each wave mean-aggregates 16 nodes into LDS (hi/lo bf16, XOR-swizzled).
// Phase 2: C = relu([self | agg] @ Wcat^T + b); self half from global, agg half from LDS.

__global__ __launch_bounds__(512) void sage_layer_fused(
    const unsigned short* __restrict__ Shi_b, const unsigned short* __restrict__ Slo_b,
    const int* __restrict__ rowptr, const int* __restrict__ eidx, const float* __restrict__ dinv,
    const unsigned short* __restrict__ Whi, const unsigned short* __restrict__ Wlo,
    const float* __restrict__ bias,
    float* __restrict__ outf_b, unsigned short* __restrict__ ohi_b, unsigned short* __restrict__ olo_b,
    int final_layer)
{
    __shared__ unsigned short Gh[128 * 128];
    __shared__ unsigned short Gl[128 * 128];

    const size_t bstr = (size_t)NN * F;
    const unsigned short* Shi = Shi_b + blockIdx.y * bstr;
    const unsigned short* Slo = Slo_b + blockIdx.y * bstr;

    int tid = threadIdx.x;
    int lane = tid & 63, wave = tid >> 6;  // 8 waves
    int g = lane >> 4, li = lane & 15;
    int nb0 = blockIdx.x * 128;

    // ---- phase 1: aggregate 16 nodes per wave ----
    for (int t = 0; t < 16; ++t) {
        int nloc = wave * 16 + t;
        int node = nb0 + nloc;
        float acc[8] = {0.f, 0.f, 0.f, 0.f, 0.f, 0.f, 0.f, 0.f};
        if (node < NN) {
            int s0 = rowptr[node], s1 = rowptr[node + 1];
            for (int e = s0; e < s1; e += 8) {
                int ea = e + g;
                int eb = e + 4 + g;
                int sa = (ea < s1) ? eidx[ea] : -1;
                int sb = (eb < s1) ? eidx[eb] : -1;
                u16x8 va, vb;
                if (sa >= 0) va = *reinterpret_cast<const u16x8*>(&Shi[(size_t)sa * F + li * 8]);
                if (sb >= 0) vb = *reinterpret_cast<const u16x8*>(&Shi[(size_t)sb * F + li * 8]);
                if (sa >= 0) {
#pragma unroll
                    for (int i = 0; i < 8; ++i) acc[i] += bf2f(va[i]);
                }
                if (sb >= 0) {
#pragma unroll
                    for (int i = 0; i < 8; ++i) acc[i] += bf2f(vb[i]);
                }
            }
        }
#pragma unroll
        for (int i = 0; i < 8; ++i) {
            acc[i] += __shfl_xor(acc[i], 16);
            acc[i] += __shfl_xor(acc[i], 32);
        }
        float di = (node < NN) ? dinv[node] : 0.f;
        u16x8 h8, l8;
#pragma unroll
        for (int i = 0; i < 8; ++i) {
            float v = acc[i] * di;
            unsigned short hh = f2bf_rn(v);
            h8[i] = hh;
            l8[i] = f2bf_rn(v - bf2f(hh));
        }
        int gr = (li ^ (nloc & 7)) * 8;   // XOR swizzle (G4): 16B granule ^= row&7
        if (g == 0) *reinterpret_cast<u16x8*>(&Gh[nloc * 128 + gr]) = h8;
        if (g == 1) *reinterpret_cast<u16x8*>(&Gl[nloc * 128 + gr]) = l8;
    }

    // ---- phase 2: MFMA ----
    int wm = wave >> 1, wn = wave & 1;
    int l15 = li, kg = g;
    int rb_loc = wm * 32;
    int rb_glob = nb0 + rb_loc;
    int col_base = wn * 64;

    f32x4 acc2[2][4];
#pragma unroll
    for (int m = 0; m < 2; ++m)
#pragma unroll
        for (int n = 0; n < 4; ++n) acc2[m][n] = (f32x4){0.f, 0.f, 0.f, 0.f};

    int arow[2];
#pragma unroll
    for (int m = 0; m < 2; ++m) arow[m] = min(rb_glob + m * 16 + l15, NN - 1);
    int bcol[4];
    float bv[4];
#pragma unroll
    for (int n = 0; n < 4; ++n) {
        bcol[n] = col_base + n * 16 + l15;
        bv[n] = bias[bcol[n]];
    }

    // self half: K = 0..127 from global
#pragma unroll
    for (int ks = 0; ks < 4; ++ks) {
        int ka = ks * 32 + kg * 8;
        bf16x8 ah[2], al[2], bh[4], bl[4];
#pragma unroll
        for (int m = 0; m < 2; ++m) {
            size_t off = (size_t)arow[m] * F + ka;
            ah[m] = *reinterpret_cast<const bf16x8*>(&Shi[off]);
            al[m] = *reinterpret_cast<const bf16x8*>(&Slo[off]);
        }
#pragma unroll
        for (int n = 0; n < 4; ++n) {
            size_t off = (size_t)bcol[n] * 256 + ka;
            bh[n] = *reinterpret_cast<const bf16x8*>(&Whi[off]);
            bl[n] = *reinterpret_cast<const bf16x8*>(&Wlo[off]);
        }
#pragma unroll
        for (int m = 0; m < 2; ++m)
#pragma unroll
            for (int n = 0; n < 4; ++n) {
                acc2[m][n] = __builtin_amdgcn_mfma_f32_16x16x32_bf16(ah[m], bh[n], acc2[m][n], 0, 0, 0);
                acc2[m][n] = __builtin_amdgcn_mfma_f32_16x16x32_bf16(ah[m], bl[n], acc2[m][n], 0, 0, 0);
                acc2[m][n] = __builtin_amdgcn_mfma_f32_16x16x32_bf16(al[m], bh[n], acc2[m][n], 0, 0, 0);
            }
    }

    __syncthreads();

    // agg half: K = 128..255 from LDS (swizzled)
#pragma unroll
    for (int ks = 4; ks < 8; ++ks) {
        int c = ks & 3;
        int kb = ks * 32 + kg * 8;
        bf16x8 ah[2], al[2], bh[4], bl[4];
#pragma unroll
        for (int m = 0; m < 2; ++m) {
            int rloc = rb_loc + m * 16 + l15;
            int gA = c * 4 + kg;
            int idx = rloc * 128 + ((gA ^ (rloc & 7)) * 8);
            ah[m] = *reinterpret_cast<const bf16x8*>(&Gh[idx]);
            al[m] = *reinterpret_cast<const bf16x8*>(&Gl[idx]);
        }
#pragma unroll
        for (int n = 0; n < 4; ++n) {
            size_t off = (size_t)bcol[n] * 256 + kb;
            bh[n] = *reinterpret_cast<const bf16x8*>(&Whi[off]);
            bl[n] = *reinterpret_cast<const bf16x8*>(&Wlo[off]);
        }
#pragma unroll
        for (int m = 0; m < 2; ++m)
#pragma unroll
            for (int n = 0; n < 4; ++n) {
                acc2[m][n] = __builtin_amdgcn_mfma_f32_16x16x32_bf16(ah[m], bh[n], acc2[m][n], 0, 0, 0);
                acc2[m][n] = __builtin_amdgcn_mfma_f32_16x16x32_bf16(ah[m], bl[n], acc2[m][n], 0, 0, 0);
                acc2[m][n] = __builtin_amdgcn_mfma_f32_16x16x32_bf16(al[m], bh[n], acc2[m][n], 0, 0, 0);
            }
    }

    // ---- epilogue ----
    float* outf = outf_b ? outf_b + blockIdx.y * bstr : nullptr;
    unsigned short* ohi = ohi_b ? ohi_b + blockIdx.y * bstr : nullptr;
    unsigned short* olo = olo_b ? olo_b + blockIdx.y * bstr : nullptr;

#pragma unroll
    for (int m = 0; m < 2; ++m) {
#pragma unroll
        for (int i = 0; i < 4; ++i) {
            int r = rb_glob + m * 16 + kg * 4 + i;
            if (r < NN) {
#pragma unroll
                for (int n = 0; n < 4; ++n) {
                    float v = fmaxf(acc2[m][n][i] + bv[n], 0.f);
                    size_t off = (size_t)r * F + bcol[n];
                    if (final_layer) {
                        outf[off] = v;
                    } else {
                        unsigned short hh = f2bf_rn(v);
                        ohi[off] = hh;
                        olo[off] = f2bf_rn(v - bf2f(hh));
                    }
                }
            }
        }
    }
}

// ---------------- launcher ----------------

extern "C" void kernel_launch(void* const* d_in, const int* in_sizes, int n_in,
                              void* d_out, int out_size, void* d_ws, size_t ws_size,
                              hipStream_t stream) {
    const float* x  = (const float*)d_in[0];
    const int* src  = (const int*)d_in[1];
    const int* dst  = (const int*)d_in[2];
    const float* Wp[3][2] = {
        {(const float*)d_in[3], (const float*)d_in[4]},
        {(const float*)d_in[6], (const float*)d_in[7]},
        {(const float*)d_in[9], (const float*)d_in[10]},
    };
    const float* bp[3] = {(const float*)d_in[5], (const float*)d_in[8], (const float*)d_in[11]};
    float* out = (float*)d_out;

    char* p = (char*)d_ws;
    auto alloc = [&](size_t b) -> void* {
        void* r = (void*)p;
        p += (b + 255) & ~(size_t)255;
        return r;
    };
    int* cnt      = (int*)alloc(sizeof(int) * NN);
    int* cursor   = (int*)alloc(sizeof(int) * NN);
    int* rowptr   = (int*)alloc(sizeof(int) * (NN + 1));
    int* local_ex = (int*)alloc(sizeof(int) * NN);
    int* bsums    = (int*)alloc(sizeof(int) * 64);
    int* eidx     = (int*)alloc(sizeof(int) * NE);
    float* dinv   = (float*)alloc(sizeof(float) * NN);
    unsigned short* Whi = (unsigned short*)alloc(sizeof(short) * 3 * 128 * 256);
    unsigned short* Wlo = (unsigned short*)alloc(sizeof(short) * 3 * 128 * 256);
    // contiguous per-batch feature buffers (ping-pong A <-> B)
    unsigned short* Ahi = (unsigned short*)alloc(sizeof(short) * NB * NN * F);
    unsigned short* Alo = (unsigned short*)alloc(sizeof(short) * NB * NN * F);
    unsigned short* Bhi = (unsigned short*)alloc(sizeof(short) * NB * NN * F);
    unsigned short* Blo = (unsigned short*)alloc(sizeof(short) * NB * NN * F);

    hipMemsetAsync(cnt, 0, (char*)rowptr - (char*)cnt, stream);  // cnt + cursor

    count_kernel<<<(NE + 255) / 256, 256, 0, stream>>>(dst, cnt);
    const int NSB = (NN + 1023) / 1024;  // 49
    scan1_kernel<<<NSB, 1024, 0, stream>>>(cnt, local_ex, bsums);
    scan2_kernel<<<1, 64, 0, stream>>>(bsums, NSB);
    scan3_kernel<<<(NN + 255) / 256, 256, 0, stream>>>(local_ex, bsums, cnt, rowptr, dinv);
    fill_kernel<<<(NE + 255) / 256, 256, 0, stream>>>(src, dst, rowptr, cursor, eidx);

    wsplit_kernel<<<3 * 128, 256, 0, stream>>>(Wp[0][0], Wp[0][1], Wp[1][0], Wp[1][1],
                                               Wp[2][0], Wp[2][1], Whi, Wlo);

    xsplit_kernel<<<((size_t)NB * NN * F / 4) / 256, 256, 0, stream>>>(x, Ahi, Alo);

    const dim3 FGRID((NN + 127) / 128, NB);  // (391, 2)

    sage_layer_fused<<<FGRID, 512, 0, stream>>>(Ahi, Alo, rowptr, eidx, dinv,
                                                Whi + 0 * 32768, Wlo + 0 * 32768, bp[0],
                                                nullptr, Bhi, Blo, 0);
    sage_layer_fused<<<FGRID, 512, 0, stream>>>(Bhi, Blo, rowptr, eidx, dinv,
                                                Whi + 1 * 32768, Wlo + 1 * 32768, bp[1],
                                                nullptr, Ahi, Alo, 0);
    sage_layer_fused<<<FGRID, 512, 0, stream>>>(Ahi, Alo, rowptr, eidx, dinv,
                                                Whi + 2 * 32768, Wlo + 2 * 32768, bp[2],
                                                out, nullptr, nullptr, 1);
}

// Round 5
// 525.053 us; speedup vs baseline: 1.1910x; 1.1910x over previous
//
#include <hip/hip_runtime.h>

#define NN 50000
#define NE 800000
#define F  128
#define NB 2
#define M2 (NB * NN)   // 100000 fused rows, layout [node][batch][feat]

typedef __attribute__((ext_vector_type(8))) short     bf16x8;
typedef __attribute__((ext_vector_type(4))) float     f32x4;
typedef __attribute__((ext_vector_type(8))) unsigned short u16x8;
typedef __attribute__((ext_vector_type(4))) unsigned short u16x4;

__device__ inline unsigned short f2bf_rn(float f) {
    unsigned u = __float_as_uint(f);
    u += 0x7FFFu + ((u >> 16) & 1u);
    return (unsigned short)(u >> 16);
}
__device__ inline float bf2f(unsigned short h) {
    return __uint_as_float(((unsigned)h) << 16);
}

// ---------------- CSR build ----------------

__global__ void count_kernel(const int* __restrict__ dst, int* __restrict__ cnt) {
    int e = blockIdx.x * blockDim.x + threadIdx.x;
    if (e < NE) atomicAdd(&cnt[dst[e]], 1);
}

__global__ __launch_bounds__(1024) void scan1_kernel(const int* __restrict__ cnt,
                                                     int* __restrict__ local_ex,
                                                     int* __restrict__ blocksums) {
    __shared__ int sd[1024];
    int i = blockIdx.x * 1024 + threadIdx.x;
    int v = (i < NN) ? cnt[i] : 0;
    sd[threadIdx.x] = v;
    __syncthreads();
    for (int off = 1; off < 1024; off <<= 1) {
        int t = 0;
        if ((int)threadIdx.x >= off) t = sd[threadIdx.x - off];
        __syncthreads();
        sd[threadIdx.x] += t;
        __syncthreads();
    }
    if (i < NN) local_ex[i] = sd[threadIdx.x] - v;  // exclusive within block
    if (threadIdx.x == 1023) blocksums[blockIdx.x] = sd[1023];
}

__global__ void scan2_kernel(int* __restrict__ bs, int nb) {
    int lane = threadIdx.x;
    int v = (lane < nb) ? bs[lane] : 0;
    for (int off = 1; off < 64; off <<= 1) {
        int t = __shfl_up(v, off);
        if (lane >= off) v += t;
    }
    int ex = __shfl_up(v, 1);
    if (lane == 0) ex = 0;
    if (lane < nb) bs[lane] = ex;
}

__global__ void scan3_kernel(const int* __restrict__ local_ex, const int* __restrict__ bs,
                             const int* __restrict__ cnt,
                             int* __restrict__ rowptr, float* __restrict__ dinv) {
    int i = blockIdx.x * blockDim.x + threadIdx.x;
    if (i < NN) {
        rowptr[i] = local_ex[i] + bs[i >> 10];
        int d = cnt[i];
        dinv[i] = (d > 0) ? 1.0f / (float)d : 0.0f;
    }
    if (i == 0) rowptr[NN] = NE;
}

__global__ void fill_kernel(const int* __restrict__ src, const int* __restrict__ dst,
                            const int* __restrict__ rowptr, int* __restrict__ cursor,
                            int* __restrict__ eidx) {
    int e = blockIdx.x * blockDim.x + threadIdx.x;
    if (e < NE) {
        int d = dst[e];
        int p = rowptr[d] + atomicAdd(&cursor[d], 1);
        __builtin_nontemporal_store(src[e], &eidx[p]);  // scattered 4B: skip write-allocate
    }
}

// ---------------- weight split (all 3 layers) ----------------

__global__ void wsplit_kernel(const float* __restrict__ Ws0, const float* __restrict__ Wn0,
                              const float* __restrict__ Ws1, const float* __restrict__ Wn1,
                              const float* __restrict__ Ws2, const float* __restrict__ Wn2,
                              unsigned short* __restrict__ hi, unsigned short* __restrict__ lo) {
    int idx = blockIdx.x * blockDim.x + threadIdx.x;  // 3*128*256
    int l = idx >> 15;
    int r = idx & 32767;
    int j = r >> 8, k = r & 255;
    const float* Ws = (l == 0) ? Ws0 : (l == 1) ? Ws1 : Ws2;
    const float* Wn = (l == 0) ? Wn0 : (l == 1) ? Wn1 : Wn2;
    float v = (k < 128) ? Ws[j * 128 + k] : Wn[j * 128 + (k - 128)];
    unsigned short h = f2bf_rn(v);
    hi[idx] = h;
    lo[idx] = f2bf_rn(v - bf2f(h));
}

// ---------------- x split: [b][n][f] fp32 -> [n][b][f] hi/lo bf16 ----------------

__global__ void xsplit_kernel(const float* __restrict__ x,
                              unsigned short* __restrict__ hi, unsigned short* __restrict__ lo) {
    size_t idx = (size_t)blockIdx.x * blockDim.x + threadIdx.x;  // NB*NN*F/4 threads
    float4 v = *reinterpret_cast<const float4*>(&x[idx * 4]);
    int f4 = (int)(idx & 31);                 // F/4 = 32 float4s per row
    size_t row = idx >> 5;                    // b*NN + n
    int b = (row >= NN) ? 1 : 0;
    size_t n = row - (size_t)b * NN;
    size_t o = ((n << 1) + b) * F + f4 * 4;   // interleaved row n*2+b
    u16x4 h4, l4;
    float vv[4] = {v.x, v.y, v.z, v.w};
#pragma unroll
    for (int i = 0; i < 4; ++i) {
        unsigned short h = f2bf_rn(vv[i]);
        h4[i] = h;
        l4[i] = f2bf_rn(vv[i] - bf2f(h));
    }
    *reinterpret_cast<u16x4*>(&hi[o]) = h4;
    *reinterpret_cast<u16x4*>(&lo[o]) = l4;
}

// ---------------- mean aggregation: 1 wave/node, both batches per edge ----------------
// h layout [node][2][128] bf16 -> one edge = one contiguous 512B row read.
// 2 edge slots (32 lanes each) x unroll 2 = 4 edges in flight.

__global__ void aggregate_bf16(const unsigned short* __restrict__ h,
                               const int* __restrict__ rowptr, const int* __restrict__ eidx,
                               const float* __restrict__ dinv,
                               unsigned short* __restrict__ agg_hi, unsigned short* __restrict__ agg_lo) {
    int gtid = blockIdx.x * blockDim.x + threadIdx.x;
    int node = gtid >> 6;
    int lane = gtid & 63;
    if (node >= NN) return;
    int g = lane >> 5, li = lane & 31;
    int s0 = rowptr[node], s1 = rowptr[node + 1];

    float acc[8] = {0.f, 0.f, 0.f, 0.f, 0.f, 0.f, 0.f, 0.f};

    for (int e = s0; e < s1; e += 4) {
        int ea = e + g;
        int eb = e + 2 + g;
        int sa = (ea < s1) ? eidx[ea] : -1;
        int sb = (eb < s1) ? eidx[eb] : -1;
        u16x8 va, vb;
        if (sa >= 0) va = *reinterpret_cast<const u16x8*>(&h[(size_t)sa * 256 + li * 8]);
        if (sb >= 0) vb = *reinterpret_cast<const u16x8*>(&h[(size_t)sb * 256 + li * 8]);
        if (sa >= 0) {
#pragma unroll
            for (int i = 0; i < 8; ++i) acc[i] += bf2f(va[i]);
        }
        if (sb >= 0) {
#pragma unroll
            for (int i = 0; i < 8; ++i) acc[i] += bf2f(vb[i]);
        }
    }

#pragma unroll
    for (int i = 0; i < 8; ++i) acc[i] += __shfl_xor(acc[i], 32);

    if (g == 0) {
        float di = dinv[node];
        u16x8 h8, l8;
#pragma unroll
        for (int i = 0; i < 8; ++i) {
            float v = acc[i] * di;
            unsigned short hh = f2bf_rn(v);
            h8[i] = hh;
            l8[i] = f2bf_rn(v - bf2f(hh));
        }
        *reinterpret_cast<u16x8*>(&agg_hi[(size_t)node * 256 + li * 8]) = h8;
        *reinterpret_cast<u16x8*>(&agg_lo[(size_t)node * 256 + li * 8]) = l8;
    }
}

// ---------------- MFMA GEMM over M2=100000 interleaved rows ----------------
// Block: 128 rows x 128 cols, 4 waves 2x2; wave 64x64 (4x4 frags of 16x16x32).

__global__ __launch_bounds__(256) void sage_gemm_mfma(
    const unsigned short* __restrict__ Shi, const unsigned short* __restrict__ Slo,
    const unsigned short* __restrict__ Ghi, const unsigned short* __restrict__ Glo,
    const unsigned short* __restrict__ Whi, const unsigned short* __restrict__ Wlo,
    const float* __restrict__ bias,
    float* __restrict__ outf, unsigned short* __restrict__ ohi, unsigned short* __restrict__ olo,
    int final_layer)
{
    int tid = threadIdx.x;
    int lane = tid & 63, wave = tid >> 6;
    int wm = wave >> 1, wn = wave & 1;
    int l15 = lane & 15, kg = lane >> 4;
    int row_base = blockIdx.x * 128 + wm * 64;
    int col_base = wn * 64;

    f32x4 acc[4][4];
#pragma unroll
    for (int m = 0; m < 4; ++m)
#pragma unroll
        for (int n = 0; n < 4; ++n) acc[m][n] = (f32x4){0.f, 0.f, 0.f, 0.f};

    int arow[4];
#pragma unroll
    for (int m = 0; m < 4; ++m) arow[m] = min(row_base + m * 16 + l15, M2 - 1);
    int bcol[4];
    float bv[4];
#pragma unroll
    for (int n = 0; n < 4; ++n) {
        bcol[n] = col_base + n * 16 + l15;
        bv[n] = bias[bcol[n]];
    }

#pragma unroll
    for (int ks = 0; ks < 8; ++ks) {
        const unsigned short* Ahi = (ks < 4) ? Shi : Ghi;
        const unsigned short* Alo = (ks < 4) ? Slo : Glo;
        int ka = (ks & 3) * 32 + kg * 8;
        int kb = ks * 32 + kg * 8;

        bf16x8 ah[4], al[4], bh[4], bl[4];
#pragma unroll
        for (int m = 0; m < 4; ++m) {
            size_t off = (size_t)arow[m] * F + ka;
            ah[m] = *reinterpret_cast<const bf16x8*>(&Ahi[off]);
            al[m] = *reinterpret_cast<const bf16x8*>(&Alo[off]);
        }
#pragma unroll
        for (int n = 0; n < 4; ++n) {
            size_t off = (size_t)bcol[n] * 256 + kb;
            bh[n] = *reinterpret_cast<const bf16x8*>(&Whi[off]);
            bl[n] = *reinterpret_cast<const bf16x8*>(&Wlo[off]);
        }

#pragma unroll
        for (int m = 0; m < 4; ++m)
#pragma unroll
            for (int n = 0; n < 4; ++n) {
                acc[m][n] = __builtin_amdgcn_mfma_f32_16x16x32_bf16(ah[m], bh[n], acc[m][n], 0, 0, 0);
                acc[m][n] = __builtin_amdgcn_mfma_f32_16x16x32_bf16(ah[m], bl[n], acc[m][n], 0, 0, 0);
                acc[m][n] = __builtin_amdgcn_mfma_f32_16x16x32_bf16(al[m], bh[n], acc[m][n], 0, 0, 0);
            }
    }

    // epilogue: C frag col=lane&15, row=(lane>>4)*4+i
#pragma unroll
    for (int m = 0; m < 4; ++m) {
#pragma unroll
        for (int i = 0; i < 4; ++i) {
            int r = row_base + m * 16 + kg * 4 + i;
            if (r < M2) {
#pragma unroll
                for (int n = 0; n < 4; ++n) {
                    float v = fmaxf(acc[m][n][i] + bv[n], 0.f);
                    if (final_layer) {
                        // r = node*2 + b  ->  out[b][node][col]
                        size_t off = ((size_t)(r & 1) * NN + (size_t)(r >> 1)) * F + bcol[n];
                        outf[off] = v;
                    } else {
                        size_t off = (size_t)r * F + bcol[n];
                        unsigned short hh = f2bf_rn(v);
                        ohi[off] = hh;
                        olo[off] = f2bf_rn(v - bf2f(hh));
                    }
                }
            }
        }
    }
}

// ---------------- launcher ----------------

extern "C" void kernel_launch(void* const* d_in, const int* in_sizes, int n_in,
                              void* d_out, int out_size, void* d_ws, size_t ws_size,
                              hipStream_t stream) {
    const float* x  = (const float*)d_in[0];
    const int* src  = (const int*)d_in[1];
    const int* dst  = (const int*)d_in[2];
    const float* Wp[3][2] = {
        {(const float*)d_in[3], (const float*)d_in[4]},
        {(const float*)d_in[6], (const float*)d_in[7]},
        {(const float*)d_in[9], (const float*)d_in[10]},
    };
    const float* bp[3] = {(const float*)d_in[5], (const float*)d_in[8], (const float*)d_in[11]};
    float* out = (float*)d_out;

    char* p = (char*)d_ws;
    auto alloc = [&](size_t b) -> void* {
        void* r = (void*)p;
        p += (b + 255) & ~(size_t)255;
        return r;
    };
    int* cnt      = (int*)alloc(sizeof(int) * NN);
    int* cursor   = (int*)alloc(sizeof(int) * NN);
    int* rowptr   = (int*)alloc(sizeof(int) * (NN + 1));
    int* local_ex = (int*)alloc(sizeof(int) * NN);
    int* bsums    = (int*)alloc(sizeof(int) * 64);
    int* eidx     = (int*)alloc(sizeof(int) * NE);
    float* dinv   = (float*)alloc(sizeof(float) * NN);
    unsigned short* Whi = (unsigned short*)alloc(sizeof(short) * 3 * 128 * 256);
    unsigned short* Wlo = (unsigned short*)alloc(sizeof(short) * 3 * 128 * 256);
    // interleaved feature buffers [node][batch][feat], ping-pong X <-> Y, agg G
    unsigned short* Xhi = (unsigned short*)alloc(sizeof(short) * M2 * F);
    unsigned short* Xlo = (unsigned short*)alloc(sizeof(short) * M2 * F);
    unsigned short* Yhi = (unsigned short*)alloc(sizeof(short) * M2 * F);
    unsigned short* Ylo = (unsigned short*)alloc(sizeof(short) * M2 * F);
    unsigned short* Ghi = (unsigned short*)alloc(sizeof(short) * M2 * F);
    unsigned short* Glo = (unsigned short*)alloc(sizeof(short) * M2 * F);

    hipMemsetAsync(cnt, 0, (char*)rowptr - (char*)cnt, stream);  // cnt + cursor

    count_kernel<<<(NE + 255) / 256, 256, 0, stream>>>(dst, cnt);
    const int NSB = (NN + 1023) / 1024;  // 49
    scan1_kernel<<<NSB, 1024, 0, stream>>>(cnt, local_ex, bsums);
    scan2_kernel<<<1, 64, 0, stream>>>(bsums, NSB);
    scan3_kernel<<<(NN + 255) / 256, 256, 0, stream>>>(local_ex, bsums, cnt, rowptr, dinv);
    fill_kernel<<<(NE + 255) / 256, 256, 0, stream>>>(src, dst, rowptr, cursor, eidx);

    wsplit_kernel<<<3 * 128, 256, 0, stream>>>(Wp[0][0], Wp[0][1], Wp[1][0], Wp[1][1],
                                               Wp[2][0], Wp[2][1], Whi, Wlo);

    xsplit_kernel<<<((size_t)NB * NN * F / 4) / 256, 256, 0, stream>>>(x, Xhi, Xlo);

    const int AGG_BLOCKS  = (NN * 64) / 256;        // 12500
    const int GEMM_BLOCKS = (M2 + 127) / 128;       // 782

    // layer 1: X -> Y
    aggregate_bf16<<<AGG_BLOCKS, 256, 0, stream>>>(Xhi, rowptr, eidx, dinv, Ghi, Glo);
    sage_gemm_mfma<<<GEMM_BLOCKS, 256, 0, stream>>>(Xhi, Xlo, Ghi, Glo,
                                                    Whi + 0 * 32768, Wlo + 0 * 32768, bp[0],
                                                    nullptr, Yhi, Ylo, 0);
    // layer 2: Y -> X
    aggregate_bf16<<<AGG_BLOCKS, 256, 0, stream>>>(Yhi, rowptr, eidx, dinv, Ghi, Glo);
    sage_gemm_mfma<<<GEMM_BLOCKS, 256, 0, stream>>>(Yhi, Ylo, Ghi, Glo,
                                                    Whi + 1 * 32768, Wlo + 1 * 32768, bp[1],
                                                    nullptr, Xhi, Xlo, 0);
    // layer 3: X -> out
    aggregate_bf16<<<AGG_BLOCKS, 256, 0, stream>>>(Xhi, rowptr, eidx, dinv, Ghi, Glo);
    sage_gemm_mfma<<<GEMM_BLOCKS, 256, 0, stream>>>(Xhi, Xlo, Ghi, Glo,
                                                    Whi + 2 * 32768, Wlo + 2 * 32768, bp[2],
                                                    out, nullptr, nullptr, 1);
}